// Round 1
// baseline (585.369 us; speedup 1.0000x reference)
//
#include <hip/hip_runtime.h>

// FusedModConv: B=4, Cin=64, H=W=512, Cout=64, K=3, wdim=512.
// v2 strategy (two-pass):
//   prep:    modulated/demodulated weights -> bf16 A-fragment-swizzled (unchanged).
//   convert: x fp32 NCHW -> bf16 "HWC" padded buffer Xp[b][h+1][w+1][ci] with a
//            zero ring (1px) so conv staging needs NO bounds checks.
//   ring:    zeroes the 1-pixel pad ring every launch (ws may be re-poisoned).
//   conv2:   implicit GEMM; x tile staged via global_load_lds (16B, async, no
//            VALU), LDS linear with chunk-XOR swizzle applied on BOTH the
//            per-lane global source address and the ds_read_b128 fragment read
//            (rule: both-sides-or-neither) -> conflict-free b-frag reads.
// Fallback: if ws_size can't hold Xp (129 MiB), use the previous single-pass conv.

typedef __bf16 bf16x8 __attribute__((ext_vector_type(8)));
typedef float f32x4 __attribute__((ext_vector_type(4)));
typedef unsigned short ushortx8 __attribute__((ext_vector_type(8)));

#define CIN   64
#define COUT  64
#define HH    512
#define WW    512
#define WDIM  512

#define TILE_H 8
#define TILE_W 32
#define XR     10   // TILE_H + 2
#define XC     34   // TILE_W + 2
#define CPAD   72   // fallback-path LDS padding

#define PW        514                       // padded H/W
#define XP_BATCH  (514 * 514 * 64)          // ushorts per batch
#define WSWZ_USH  147456                    // 4 * 36864 ushorts = 294912 B
#define NEED_WS   (294912ull + 4ull * 514 * 514 * 64 * 2)  // 135,563,264 B

__device__ __forceinline__ unsigned short f2bf(float f) {
    unsigned int u = __float_as_uint(f);
    unsigned int r = (u + 0x7FFFu + ((u >> 16) & 1u)) >> 16;  // RNE
    return (unsigned short)r;
}

// ---------------------------------------------------------------------------
// prep: style = w @ (rc*mod_w) + mod_b + 1; wt = rc_conv*conv_w*style;
// d = rsqrt(sum wt^2 + 1e-8); write bf16 weights swizzled as A-fragments:
//   co = mfrag*16 + (lane&15),  ci = kstep*32 + (lane>>4)*8 + j
// ---------------------------------------------------------------------------
__global__ void prep_kernel(const float* __restrict__ wv,
                            const float* __restrict__ conv_w,
                            const float* __restrict__ mod_w,
                            const float* __restrict__ mod_b,
                            unsigned short* __restrict__ Wswz) {
    const int b    = blockIdx.x;
    const int tid  = threadIdx.x;
    const int lane6 = tid & 63;
    const int part  = tid >> 6;
    __shared__ float red[256];
    __shared__ float style[64];
    __shared__ float dsc[64];
    const float rc_dense = 0.04419417382415922f;   // 1/sqrt(512)
    const float rc_conv  = 0.041666666666666664f;  // 1/sqrt(9*64)

    float s = 0.f;
    const float* wb = wv + b * WDIM;
    for (int k = part * 128; k < part * 128 + 128; ++k)
        s += wb[k] * mod_w[k * 64 + lane6];
    red[tid] = s;
    __syncthreads();
    if (part == 0) {
        float tot = red[lane6] + red[64 + lane6] + red[128 + lane6] + red[192 + lane6];
        style[lane6] = tot * rc_dense + mod_b[lane6] + 1.0f;
    }
    __syncthreads();

    float qq = 0.f;
    for (int idx = part * 144; idx < part * 144 + 144; ++idx) {
        float v = conv_w[idx * 64 + lane6] * style[idx & 63];  // idx = tap*64+ci
        qq += v * v;
    }
    red[tid] = qq;
    __syncthreads();
    if (part == 0) {
        float tot = red[lane6] + red[64 + lane6] + red[128 + lane6] + red[192 + lane6];
        dsc[lane6] = rsqrtf(rc_conv * rc_conv * tot + 1e-8f);
    }
    __syncthreads();

    for (int it = 0; it < 18; ++it) {
        int id  = it * 256 + tid;      // 0..4607
        int l   = id & 63;
        int mf  = (id >> 6) & 3;
        int ks  = (id >> 8) & 1;
        int t   = id >> 9;             // 0..8
        int co  = mf * 16 + (l & 15);
        int ci0 = ks * 32 + (l >> 4) * 8;
        float fco = rc_conv * dsc[co];
        ushortx8 ov;
#pragma unroll
        for (int j = 0; j < 8; ++j) {
            int ci = ci0 + j;
            float v = conv_w[(t * 64 + ci) * 64 + co] * style[ci] * fco;
            ov[j] = f2bf(v);
        }
        *reinterpret_cast<ushortx8*>(Wswz + (size_t)b * 36864 + id * 8) = ov;
    }
}

// ---------------------------------------------------------------------------
// ring: zero the 1-pixel pad ring of Xp (2052 px * 8 chunks * 4 batches).
// ---------------------------------------------------------------------------
__global__ void ring_kernel(unsigned short* __restrict__ Xp) {
    int id = blockIdx.x * 256 + threadIdx.x;
    if (id >= 65664) return;               // 4 * 2052 * 8
    int b  = id / 16416;
    int r  = id - b * 16416;
    int px = r >> 3, ck = r & 7;
    int rp, cp;
    if (px < 514)       { rp = 0;             cp = px; }
    else if (px < 1028) { rp = 513;           cp = px - 514; }
    else if (px < 1540) { rp = px - 1028 + 1; cp = 0; }
    else                { rp = px - 1540 + 1; cp = 513; }
    ushortx8 z = {0, 0, 0, 0, 0, 0, 0, 0};
    *reinterpret_cast<ushortx8*>(
        Xp + (size_t)b * XP_BATCH + ((size_t)rp * PW + cp) * 64 + ck * 8) = z;
}

// ---------------------------------------------------------------------------
// convert: x fp32 NCHW -> bf16 Xp[b][h+1][w+1][ci] (interior only).
// Lane mapping: ck (ci-chunk of 8) fastest -> 8 lanes cover one 128B pixel;
// stores are 1KiB-contiguous per wave. Loads: 8 x 32B segments per instr.
// NT loads: x is read exactly once; keep L3 for Xp.
// ---------------------------------------------------------------------------
__global__ __launch_bounds__(256) void convert_kernel(const float* __restrict__ x,
                                                      unsigned short* __restrict__ Xp) {
    const int tid = threadIdx.x;
    const int blk = blockIdx.x;
#pragma unroll
    for (int it = 0; it < 4; ++it) {
        unsigned id = (unsigned)blk * 1024u + (unsigned)(it * 256 + tid);  // < 2^23
        int ck = id & 7;
        int w  = (id >> 3) & 511;
        int h  = (id >> 12) & 511;
        int b  = id >> 21;
        const float* xp = x + ((size_t)(b * 64 + ck * 8) * (HH * WW) + (size_t)h * WW + w);
        ushortx8 v;
#pragma unroll
        for (int j = 0; j < 8; ++j)
            v[j] = f2bf(__builtin_nontemporal_load(xp + (size_t)j * (HH * WW)));
        *reinterpret_cast<ushortx8*>(
            Xp + (size_t)b * XP_BATCH + ((size_t)(h + 1) * PW + (w + 1)) * 64 + ck * 8) = v;
    }
}

// ---------------------------------------------------------------------------
// conv2: one block = one (b, 8x32 tile), 256 threads = 4 waves.
// Stage: 2720 16B chunks via global_load_lds, LDS linear [r][c][ci] (no pad),
// chunk index XOR (c&7) applied on the global source AND on the frag read.
// ---------------------------------------------------------------------------
__global__ __launch_bounds__(256, 3) void conv2_kernel(
        const unsigned short* __restrict__ Xp,
        const unsigned short* __restrict__ Wswz,
        float* __restrict__ out) {
    __shared__ alignas(16) unsigned short xs[XR * XC * 64];  // 43520 B

    const int tid  = threadIdx.x;
    const int blk  = blockIdx.x;
    const int b    = blk >> 10;
    const int tile = blk & 1023;
    const int tr   = tile >> 4;
    const int tc   = tile & 15;
    const int h0   = tr * TILE_H;          // == first staged padded row
    const int w0   = tc * TILE_W;          // == first staged padded col
    const unsigned short* Xpb = Xp + (size_t)b * XP_BATCH;
    const int wv = tid >> 6, l = tid & 63;

    // ---- async stage: 2720 chunks = 10 rows x 34 px x 8 ci-chunks ----
    for (int it = 0; it < 11; ++it) {
        unsigned id = (unsigned)(it * 256 + tid);
        if (id < 2720u) {
            unsigned row = id / 272u;            // 272 = 34*8
            unsigned rc  = id - row * 272u;
            unsigned pc  = rc >> 3;
            unsigned ck  = rc & 7u;
            unsigned g   = ck ^ (pc & 7u);       // source-side swizzle
            const unsigned short* gp =
                Xpb + ((size_t)(h0 + (int)row) * PW + (w0 + (int)pc)) * 64 + g * 8;
            unsigned short* lp = xs + (size_t)(it * 256 + wv * 64) * 8;  // wave-uniform
            __builtin_amdgcn_global_load_lds(
                (const __attribute__((address_space(1))) void*)gp,
                (__attribute__((address_space(3))) void*)lp, 16, 0, 0);
        }
    }
    __syncthreads();  // drains vmcnt

    // ---- implicit GEMM main loop ----
    const int m16 = l & 15;
    const int q   = l >> 4;

    f32x4 acc[4][4];
#pragma unroll
    for (int mf = 0; mf < 4; ++mf)
#pragma unroll
        for (int nf = 0; nf < 4; ++nf)
            acc[mf][nf] = (f32x4){0.f, 0.f, 0.f, 0.f};

    int pix0[4], pc0[4];
#pragma unroll
    for (int nf = 0; nf < 4; ++nf) {
        int np = (wv * 4 + nf) * 16 + m16;   // pixel index in tile
        int pr = np >> 5, pc = np & 31;
        pix0[nf] = pr * XC + pc;
        pc0[nf]  = pc;
    }
    const unsigned short* Wb = Wswz + (size_t)b * 36864 + l * 8;

#pragma unroll
    for (int kh = 0; kh < 3; ++kh)
#pragma unroll
        for (int kw = 0; kw < 3; ++kw) {
            const int t = kh * 3 + kw;
#pragma unroll
            for (int s = 0; s < 2; ++s) {
                const unsigned short* Wt = Wb + (t * 2 + s) * 2048;
                bf16x8 a[4], bb[4];
#pragma unroll
                for (int mf = 0; mf < 4; ++mf)
                    a[mf] = *reinterpret_cast<const bf16x8*>(Wt + mf * 512);
#pragma unroll
                for (int nf = 0; nf < 4; ++nf) {
                    int pix = pix0[nf] + kh * XC + kw;
                    int ck  = (s * 4 + q) ^ ((pc0[nf] + kw) & 7);  // read-side swizzle
                    bb[nf] = *reinterpret_cast<const bf16x8*>(&xs[pix * 64 + ck * 8]);
                }
#pragma unroll
                for (int mf = 0; mf < 4; ++mf)
#pragma unroll
                    for (int nf = 0; nf < 4; ++nf)
                        acc[mf][nf] = __builtin_amdgcn_mfma_f32_16x16x32_bf16(
                            a[mf], bb[nf], acc[mf][nf], 0, 0, 0);
            }
        }

    // ---- epilogue: C/D layout col=lane&15 (pixel), row=q*4+reg (co) ----
    float* ob = out + (size_t)b * COUT * HH * WW;
#pragma unroll
    for (int nf = 0; nf < 4; ++nf) {
        int np = (wv * 4 + nf) * 16 + m16;
        int pr = np >> 5, pc = np & 31;
        int h = h0 + pr, wc = w0 + pc;
#pragma unroll
        for (int mf = 0; mf < 4; ++mf) {
            int co = mf * 16 + q * 4;
            float* po = ob + ((size_t)co * HH + h) * WW + wc;
#pragma unroll
            for (int reg = 0; reg < 4; ++reg)
                __builtin_nontemporal_store(acc[mf][nf][reg], po + (size_t)reg * HH * WW);
        }
    }
}

// ---------------------------------------------------------------------------
// fallback conv (previous single-pass kernel, used when ws is too small)
// ---------------------------------------------------------------------------
__global__ __launch_bounds__(256, 3) void conv_kernel(
        const float* __restrict__ x,
        const unsigned short* __restrict__ Wswz,
        float* __restrict__ out) {
    __shared__ unsigned short xs[XR * XC * CPAD];  // 48960 B

    const int tid  = threadIdx.x;
    const int blk  = blockIdx.x;
    const int b    = blk >> 10;
    const int tile = blk & 1023;
    const int tr   = tile >> 4;
    const int tc   = tile & 15;
    const int h0   = tr * TILE_H;
    const int w0   = tc * TILE_W;
    const float* xb = x + (size_t)b * CIN * HH * WW;

    for (int it = 0; it < 11; ++it) {
        int id = it * 256 + tid;
        if (id < 2720) {
            int c   = id % 34;
            int rem = id / 34;
            int r   = rem % 10;
            int o8  = rem / 10;
            int rg  = h0 + r - 1;
            int cg  = w0 + c - 1;
            ushortx8 v;
            if (((unsigned)rg < (unsigned)HH) && ((unsigned)cg < (unsigned)WW)) {
                const float* p = xb + ((size_t)(o8 * 8) * HH + rg) * WW + cg;
#pragma unroll
                for (int j = 0; j < 8; ++j)
                    v[j] = f2bf(p[(size_t)j * HH * WW]);
            } else {
#pragma unroll
                for (int j = 0; j < 8; ++j) v[j] = 0;
            }
            *reinterpret_cast<ushortx8*>(&xs[(r * XC + c) * CPAD + o8 * 8]) = v;
        }
    }
    __syncthreads();

    const int l   = tid & 63;
    const int wv  = tid >> 6;
    const int m16 = l & 15;
    const int q   = l >> 4;

    f32x4 acc[4][4];
#pragma unroll
    for (int mf = 0; mf < 4; ++mf)
#pragma unroll
        for (int nf = 0; nf < 4; ++nf)
            acc[mf][nf] = (f32x4){0.f, 0.f, 0.f, 0.f};

    int Xbase[4];
#pragma unroll
    for (int nf = 0; nf < 4; ++nf) {
        int np = (wv * 4 + nf) * 16 + m16;
        int pr = np >> 5, pc = np & 31;
        Xbase[nf] = (pr * XC + pc) * CPAD + q * 8;
    }
    const unsigned short* Wb = Wswz + (size_t)b * 36864 + l * 8;

    for (int kh = 0; kh < 3; ++kh) {
        for (int kw = 0; kw < 3; ++kw) {
            int t = kh * 3 + kw;
#pragma unroll
            for (int s = 0; s < 2; ++s) {
                const unsigned short* Wt = Wb + (t * 2 + s) * 2048;
                bf16x8 a[4], bb[4];
#pragma unroll
                for (int mf = 0; mf < 4; ++mf)
                    a[mf] = *reinterpret_cast<const bf16x8*>(Wt + mf * 512);
                int so = (kh * XC + kw) * CPAD + s * 32;
#pragma unroll
                for (int nf = 0; nf < 4; ++nf)
                    bb[nf] = *reinterpret_cast<const bf16x8*>(&xs[Xbase[nf] + so]);
#pragma unroll
                for (int mf = 0; mf < 4; ++mf)
#pragma unroll
                    for (int nf = 0; nf < 4; ++nf)
                        acc[mf][nf] = __builtin_amdgcn_mfma_f32_16x16x32_bf16(
                            a[mf], bb[nf], acc[mf][nf], 0, 0, 0);
            }
        }
    }

    float* ob = out + (size_t)b * COUT * HH * WW;
#pragma unroll
    for (int nf = 0; nf < 4; ++nf) {
        int np = (wv * 4 + nf) * 16 + m16;
        int pr = np >> 5, pc = np & 31;
        int h = h0 + pr, wc = w0 + pc;
#pragma unroll
        for (int mf = 0; mf < 4; ++mf) {
            int co = mf * 16 + q * 4;
            float* po = ob + ((size_t)co * HH + h) * WW + wc;
#pragma unroll
            for (int reg = 0; reg < 4; ++reg)
                po[(size_t)reg * HH * WW] = acc[mf][nf][reg];
        }
    }
}

extern "C" void kernel_launch(void* const* d_in, const int* in_sizes, int n_in,
                              void* d_out, int out_size, void* d_ws, size_t ws_size,
                              hipStream_t stream) {
    const float* x      = (const float*)d_in[0];
    const float* w      = (const float*)d_in[1];
    const float* conv_w = (const float*)d_in[2];
    const float* mod_w  = (const float*)d_in[3];
    const float* mod_b  = (const float*)d_in[4];
    float* out = (float*)d_out;
    unsigned short* Wswz = (unsigned short*)d_ws;

    prep_kernel<<<4, 256, 0, stream>>>(w, conv_w, mod_w, mod_b, Wswz);

    if (ws_size >= NEED_WS) {
        unsigned short* Xp = Wswz + WSWZ_USH;
        ring_kernel<<<257, 256, 0, stream>>>(Xp);
        convert_kernel<<<8192, 256, 0, stream>>>(x, Xp);
        conv2_kernel<<<4096, 256, 0, stream>>>(Xp, Wswz, out);
    } else {
        conv_kernel<<<4096, 256, 0, stream>>>(x, Wswz, out);
    }
}